// Round 1
// baseline (750.937 us; speedup 1.0000x reference)
//
#include <hip/hip_runtime.h>

#define N_NODES 50000
#define N_EDGES 800000
#define D_FEAT  64

// Baseline: push-style scatter-add.
// 16 threads per edge; each thread handles 4 contiguous features (float4 read,
// 4x fp32 atomicAdd). queue (12.8 MB) is L2/LLC resident, so the gather is
// cheap; the expected bottleneck is the 51.2M fp32 atomics at the TCC.
__global__ void __launch_bounds__(256)
scatter_add_kernel(const float* __restrict__ queue,
                   const float* __restrict__ weight,
                   const int* __restrict__ src,
                   const int* __restrict__ dst,
                   float* __restrict__ out) {
    long long tid = (long long)blockIdx.x * blockDim.x + threadIdx.x;
    int e = (int)(tid >> 4);          // edge index
    int c = ((int)tid & 15) << 2;     // feature offset (0,4,...,60)
    if (e >= N_EDGES) return;

    int s = src[e];
    int d = dst[e];
    float w = weight[e];

    const float4 q = *reinterpret_cast<const float4*>(queue + (size_t)s * D_FEAT + c);
    float* o = out + (size_t)d * D_FEAT + c;

    atomicAdd(o + 0, q.x * w);
    atomicAdd(o + 1, q.y * w);
    atomicAdd(o + 2, q.z * w);
    atomicAdd(o + 3, q.w * w);
}

extern "C" void kernel_launch(void* const* d_in, const int* in_sizes, int n_in,
                              void* d_out, int out_size, void* d_ws, size_t ws_size,
                              hipStream_t stream) {
    const float* queue  = (const float*)d_in[0];
    const float* weight = (const float*)d_in[1];
    const int*   src    = (const int*)d_in[2];
    const int*   dst    = (const int*)d_in[3];
    float* out = (float*)d_out;

    // d_out is re-poisoned to 0xAA before every timed launch — zero it first.
    hipMemsetAsync(out, 0, (size_t)out_size * sizeof(float), stream);

    const int threads_per_edge = 16;
    const long long total = (long long)N_EDGES * threads_per_edge;  // 12.8M
    const int block = 256;
    const int grid = (int)((total + block - 1) / block);            // 50000

    scatter_add_kernel<<<grid, block, 0, stream>>>(queue, weight, src, dst, out);
}

// Round 2
// 339.822 us; speedup vs baseline: 2.2098x; 2.2098x over previous
//
#include <hip/hip_runtime.h>

#define N_NODES 50000
#define N_EDGES 800000
#define D_FEAT  64

// ---------------------------------------------------------------------------
// Round 2: pull-based segment-sum via per-launch CSR build in d_ws.
//   1. memset counts
//   2. histogram of dst           (800K atomics on 50K counters)
//   3. single-block exclusive scan -> offsets + cursor
//   4. fill CSR with packed (src, weight_bits) per edge (800K atomics)
//   5. pull: one wave per node, lane = feature; register accumulate, one
//      coalesced 256B store per node. Zero atomics in the hot path.
// ---------------------------------------------------------------------------

__global__ void __launch_bounds__(256)
hist_kernel(const int* __restrict__ dst, int* __restrict__ counts) {
    int e = blockIdx.x * blockDim.x + threadIdx.x;
    if (e < N_EDGES) atomicAdd(&counts[dst[e]], 1);
}

#define SCAN_THREADS 1024
__global__ void __launch_bounds__(SCAN_THREADS)
scan_kernel(const int* __restrict__ counts, int* __restrict__ offsets,
            int* __restrict__ cursor) {
    __shared__ int sums[SCAN_THREADS];
    const int t = threadIdx.x;
    const int chunk = (N_NODES + SCAN_THREADS - 1) / SCAN_THREADS;  // 49
    const int beg = t * chunk;
    const int end = min(beg + chunk, N_NODES);

    int local = 0;
    for (int i = beg; i < end; ++i) local += counts[i];
    sums[t] = local;
    __syncthreads();

    // Hillis-Steele inclusive scan over the 1024 partials.
    for (int off = 1; off < SCAN_THREADS; off <<= 1) {
        int v = (t >= off) ? sums[t - off] : 0;
        __syncthreads();
        sums[t] += v;
        __syncthreads();
    }

    int run = (t == 0) ? 0 : sums[t - 1];  // exclusive base for this chunk
    for (int i = beg; i < end; ++i) {
        offsets[i] = run;
        cursor[i]  = run;
        run += counts[i];
    }
    if (t == SCAN_THREADS - 1) offsets[N_NODES] = run;  // == N_EDGES
}

__global__ void __launch_bounds__(256)
fill_kernel(const int* __restrict__ src, const int* __restrict__ dst,
            const float* __restrict__ weight, int* __restrict__ cursor,
            uint2* __restrict__ csr) {
    int e = blockIdx.x * blockDim.x + threadIdx.x;
    if (e >= N_EDGES) return;
    int d = dst[e];
    int pos = atomicAdd(&cursor[d], 1);
    csr[pos] = make_uint2((unsigned)src[e], __float_as_uint(weight[e]));
}

// One 64-lane wave per node; 4 nodes per 256-thread block.
__global__ void __launch_bounds__(256)
pull_kernel(const float* __restrict__ queue, const uint2* __restrict__ csr,
            const int* __restrict__ offsets, float* __restrict__ out) {
    const int node = blockIdx.x * 4 + (threadIdx.x >> 6);
    const int lane = threadIdx.x & 63;
    if (node >= N_NODES) return;

    const int beg = offsets[node];
    const int end = offsets[node + 1];

    float acc = 0.0f;
    for (int i = beg; i < end; ++i) {
        uint2 ent = csr[i];  // wave-uniform 8B broadcast load
        float w = __uint_as_float(ent.y);
        acc = fmaf(queue[(size_t)ent.x * D_FEAT + lane], w, acc);
    }
    out[(size_t)node * D_FEAT + lane] = acc;  // coalesced 256B per wave
}

// --- Fallback (round-1 scatter) if ws_size is ever too small ---------------
__global__ void __launch_bounds__(256)
scatter_add_kernel(const float* __restrict__ queue,
                   const float* __restrict__ weight,
                   const int* __restrict__ src,
                   const int* __restrict__ dst,
                   float* __restrict__ out) {
    long long tid = (long long)blockIdx.x * blockDim.x + threadIdx.x;
    int e = (int)(tid >> 4);
    int c = ((int)tid & 15) << 2;
    if (e >= N_EDGES) return;
    int s = src[e], d = dst[e];
    float w = weight[e];
    const float4 q = *reinterpret_cast<const float4*>(queue + (size_t)s * D_FEAT + c);
    float* o = out + (size_t)d * D_FEAT + c;
    atomicAdd(o + 0, q.x * w);
    atomicAdd(o + 1, q.y * w);
    atomicAdd(o + 2, q.z * w);
    atomicAdd(o + 3, q.w * w);
}

extern "C" void kernel_launch(void* const* d_in, const int* in_sizes, int n_in,
                              void* d_out, int out_size, void* d_ws, size_t ws_size,
                              hipStream_t stream) {
    const float* queue  = (const float*)d_in[0];
    const float* weight = (const float*)d_in[1];
    const int*   src    = (const int*)d_in[2];
    const int*   dst    = (const int*)d_in[3];
    float* out = (float*)d_out;

    // Workspace layout (8B-aligned csr first):
    //   csr:     N_EDGES uint2            (6.4 MB)
    //   counts:  N_NODES int
    //   offsets: N_NODES+1 int
    //   cursor:  N_NODES int
    const size_t csr_bytes = (size_t)N_EDGES * sizeof(uint2);
    const size_t need = csr_bytes + (size_t)(3 * N_NODES + 2) * sizeof(int);

    if (ws_size < need) {  // safety fallback: round-1 scatter path
        hipMemsetAsync(out, 0, (size_t)out_size * sizeof(float), stream);
        const long long total = (long long)N_EDGES * 16;
        scatter_add_kernel<<<(int)((total + 255) / 256), 256, 0, stream>>>(
            queue, weight, src, dst, out);
        return;
    }

    char* ws = (char*)d_ws;
    uint2* csr    = (uint2*)ws;
    int* counts   = (int*)(ws + csr_bytes);
    int* offsets  = counts + N_NODES;
    int* cursor   = offsets + (N_NODES + 1);

    hipMemsetAsync(counts, 0, (size_t)N_NODES * sizeof(int), stream);

    const int eblocks = (N_EDGES + 255) / 256;  // 3125
    hist_kernel<<<eblocks, 256, 0, stream>>>(dst, counts);
    scan_kernel<<<1, SCAN_THREADS, 0, stream>>>(counts, offsets, cursor);
    fill_kernel<<<eblocks, 256, 0, stream>>>(src, dst, weight, cursor, csr);

    const int nblocks = (N_NODES + 3) / 4;  // 12500, 4 nodes (waves) / block
    pull_kernel<<<nblocks, 256, 0, stream>>>(queue, csr, offsets, out);
}

// Round 3
// 249.434 us; speedup vs baseline: 3.0106x; 1.3624x over previous
//
#include <hip/hip_runtime.h>

#define N_NODES 50000
#define N_EDGES 800000
#define D_FEAT  64

// ---------------------------------------------------------------------------
// Round 3: pull-based segment-sum; scan replaced by atomic segment allocator.
//   1. memset counts + galloc (one contiguous memset)
//   2. hist:  counts[dst[e]]++                      (800K int atomics)
//   3. alloc: base = atomicAdd(galloc, counts[i])   (50K int atomics)
//             -> beg[i], cursor[i].  Segments are contiguous but in
//             ARBITRARY node order — pull only needs beg+count, not order.
//   4. fill:  csr[atomicAdd(&cursor[dst],1)] = (src, weight)
//   5. pull:  one wave per node, lane = feature; register accumulate,
//             one coalesced 256B store. Zero atomics in the hot path.
// ---------------------------------------------------------------------------

__global__ void __launch_bounds__(256)
hist_kernel(const int* __restrict__ dst, int* __restrict__ counts) {
    int e = blockIdx.x * blockDim.x + threadIdx.x;
    if (e < N_EDGES) atomicAdd(&counts[dst[e]], 1);
}

__global__ void __launch_bounds__(256)
alloc_kernel(const int* __restrict__ counts, int* __restrict__ beg,
             int* __restrict__ cursor, int* __restrict__ galloc) {
    int i = blockIdx.x * blockDim.x + threadIdx.x;
    if (i >= N_NODES) return;
    int c = counts[i];
    int base = atomicAdd(galloc, c);
    beg[i] = base;
    cursor[i] = base;
}

__global__ void __launch_bounds__(256)
fill_kernel(const int* __restrict__ src, const int* __restrict__ dst,
            const float* __restrict__ weight, int* __restrict__ cursor,
            uint2* __restrict__ csr) {
    int e = blockIdx.x * blockDim.x + threadIdx.x;
    if (e >= N_EDGES) return;
    int d = dst[e];
    int pos = atomicAdd(&cursor[d], 1);
    csr[pos] = make_uint2((unsigned)src[e], __float_as_uint(weight[e]));
}

// One 64-lane wave per node; 4 nodes per 256-thread block.
__global__ void __launch_bounds__(256)
pull_kernel(const float* __restrict__ queue, const uint2* __restrict__ csr,
            const int* __restrict__ beg, const int* __restrict__ counts,
            float* __restrict__ out) {
    const int node = blockIdx.x * 4 + (threadIdx.x >> 6);
    const int lane = threadIdx.x & 63;
    if (node >= N_NODES) return;

    const int b = beg[node];
    const int e = b + counts[node];

    float acc = 0.0f;
    for (int i = b; i < e; ++i) {
        uint2 ent = csr[i];  // wave-uniform 8B broadcast load
        float w = __uint_as_float(ent.y);
        acc = fmaf(queue[(size_t)ent.x * D_FEAT + lane], w, acc);
    }
    out[(size_t)node * D_FEAT + lane] = acc;  // coalesced 256B per wave
}

// --- Fallback (round-1 scatter) if ws_size is ever too small ---------------
__global__ void __launch_bounds__(256)
scatter_add_kernel(const float* __restrict__ queue,
                   const float* __restrict__ weight,
                   const int* __restrict__ src,
                   const int* __restrict__ dst,
                   float* __restrict__ out) {
    long long tid = (long long)blockIdx.x * blockDim.x + threadIdx.x;
    int e = (int)(tid >> 4);
    int c = ((int)tid & 15) << 2;
    if (e >= N_EDGES) return;
    int s = src[e], d = dst[e];
    float w = weight[e];
    const float4 q = *reinterpret_cast<const float4*>(queue + (size_t)s * D_FEAT + c);
    float* o = out + (size_t)d * D_FEAT + c;
    atomicAdd(o + 0, q.x * w);
    atomicAdd(o + 1, q.y * w);
    atomicAdd(o + 2, q.z * w);
    atomicAdd(o + 3, q.w * w);
}

extern "C" void kernel_launch(void* const* d_in, const int* in_sizes, int n_in,
                              void* d_out, int out_size, void* d_ws, size_t ws_size,
                              hipStream_t stream) {
    const float* queue  = (const float*)d_in[0];
    const float* weight = (const float*)d_in[1];
    const int*   src    = (const int*)d_in[2];
    const int*   dst    = (const int*)d_in[3];
    float* out = (float*)d_out;

    // Workspace layout:
    //   csr:    N_EDGES uint2   (6.4 MB)
    //   counts: N_NODES int     \ zeroed together (galloc adjacent to counts)
    //   galloc: 1 int           /
    //   beg:    N_NODES int
    //   cursor: N_NODES int
    const size_t csr_bytes = (size_t)N_EDGES * sizeof(uint2);
    const size_t need = csr_bytes + (size_t)(3 * N_NODES + 1) * sizeof(int);

    if (ws_size < need) {  // safety fallback: round-1 scatter path
        hipMemsetAsync(out, 0, (size_t)out_size * sizeof(float), stream);
        const long long total = (long long)N_EDGES * 16;
        scatter_add_kernel<<<(int)((total + 255) / 256), 256, 0, stream>>>(
            queue, weight, src, dst, out);
        return;
    }

    char* ws = (char*)d_ws;
    uint2* csr   = (uint2*)ws;
    int* counts  = (int*)(ws + csr_bytes);
    int* galloc  = counts + N_NODES;
    int* beg     = galloc + 1;
    int* cursor  = beg + N_NODES;

    hipMemsetAsync(counts, 0, (size_t)(N_NODES + 1) * sizeof(int), stream);

    const int eblocks = (N_EDGES + 255) / 256;  // 3125
    const int nthreads_blocks = (N_NODES + 255) / 256;  // 196

    hist_kernel<<<eblocks, 256, 0, stream>>>(dst, counts);
    alloc_kernel<<<nthreads_blocks, 256, 0, stream>>>(counts, beg, cursor, galloc);
    fill_kernel<<<eblocks, 256, 0, stream>>>(src, dst, weight, cursor, csr);

    const int nblocks = (N_NODES + 3) / 4;  // 12500, 4 nodes (waves) / block
    pull_kernel<<<nblocks, 256, 0, stream>>>(queue, csr, beg, counts, out);
}

// Round 4
// 200.226 us; speedup vs baseline: 3.7504x; 1.2458x over previous
//
#include <hip/hip_runtime.h>
#include <hip/hip_fp16.h>

#define N_NODES 50000
#define N_EDGES 800000
#define D_FEAT  64
// CSR capacity: every node segment rounded up to multiple of 4 entries.
#define CSR_CAP (N_EDGES + 4 * N_NODES)   // 1,000,000 entries x 4B = 4 MB

// ---------------------------------------------------------------------------
// Round 4: 4B-packed CSR (src<<16 | fp16(weight)), segments padded to x4 with
// zero-weight entries so pull reads aligned uint4 and unrolls x8 for MLP.
//   1. memset counts+galloc
//   2. hist  (int4-vectorized reads, 800K atomics)
//   3. alloc (atomic segment allocator; rounds to x4, writes pad entries)
//   4. fill  (int4/float4 reads, 4B scattered stores, 800K atomics)
//   5. pull  (one wave/node, uint4 csr loads, 8 gathers in flight)
// ---------------------------------------------------------------------------

__device__ __forceinline__ unsigned pack_entry(int s, float w) {
    return ((unsigned)s << 16) | (unsigned)__half_as_ushort(__float2half(w));
}
__device__ __forceinline__ float entry_w(unsigned e) {
    return __half2float(__ushort_as_half((unsigned short)(e & 0xffffu)));
}

__global__ void __launch_bounds__(256)
hist_kernel(const int* __restrict__ dst, int* __restrict__ counts) {
    int t = blockIdx.x * blockDim.x + threadIdx.x;   // 200000 threads
    if (t * 4 >= N_EDGES) return;
    int4 d = *reinterpret_cast<const int4*>(dst + t * 4);
    atomicAdd(&counts[d.x], 1);
    atomicAdd(&counts[d.y], 1);
    atomicAdd(&counts[d.z], 1);
    atomicAdd(&counts[d.w], 1);
}

__global__ void __launch_bounds__(256)
alloc_kernel(const int* __restrict__ counts, uint2* __restrict__ seg,
             int* __restrict__ cursor, int* __restrict__ galloc,
             unsigned* __restrict__ csr) {
    int i = blockIdx.x * blockDim.x + threadIdx.x;
    if (i >= N_NODES) return;
    int c  = counts[i];
    int c4 = (c + 3) & ~3;                 // round segment to multiple of 4
    int base = atomicAdd(galloc, c4);
    seg[i]    = make_uint2((unsigned)base, (unsigned)c4);
    cursor[i] = base;
    for (int k = c; k < c4; ++k) csr[base + k] = 0u;  // src=0, w=+0.0f pads
}

__global__ void __launch_bounds__(256)
fill_kernel(const int* __restrict__ src, const int* __restrict__ dst,
            const float* __restrict__ weight, int* __restrict__ cursor,
            unsigned* __restrict__ csr) {
    int t = blockIdx.x * blockDim.x + threadIdx.x;   // 200000 threads
    if (t * 4 >= N_EDGES) return;
    int4   s = *reinterpret_cast<const int4*>(src + t * 4);
    int4   d = *reinterpret_cast<const int4*>(dst + t * 4);
    float4 w = *reinterpret_cast<const float4*>(weight + t * 4);
    int p;
    p = atomicAdd(&cursor[d.x], 1); csr[p] = pack_entry(s.x, w.x);
    p = atomicAdd(&cursor[d.y], 1); csr[p] = pack_entry(s.y, w.y);
    p = atomicAdd(&cursor[d.z], 1); csr[p] = pack_entry(s.z, w.z);
    p = atomicAdd(&cursor[d.w], 1); csr[p] = pack_entry(s.w, w.w);
}

// One 64-lane wave per node; 4 nodes per 256-thread block.
// Segments are 16B-aligned multiples of 4 entries -> branchless uint4 loads.
__global__ void __launch_bounds__(256)
pull_kernel(const float* __restrict__ queue, const unsigned* __restrict__ csr,
            const uint2* __restrict__ seg, float* __restrict__ out) {
    const int node = blockIdx.x * 4 + (threadIdx.x >> 6);
    const int lane = threadIdx.x & 63;
    if (node >= N_NODES) return;

    const uint2 sg = seg[node];
    const unsigned* p = csr + sg.x;
    const unsigned n4 = sg.y;

    float acc = 0.0f;
    unsigned i = 0;
    // 8 independent gathers in flight per iteration.
    for (; i + 8 <= n4; i += 8) {
        uint4 ea = *reinterpret_cast<const uint4*>(p + i);
        uint4 eb = *reinterpret_cast<const uint4*>(p + i + 4);
        float q0 = queue[(size_t)(ea.x >> 16) * D_FEAT + lane];
        float q1 = queue[(size_t)(ea.y >> 16) * D_FEAT + lane];
        float q2 = queue[(size_t)(ea.z >> 16) * D_FEAT + lane];
        float q3 = queue[(size_t)(ea.w >> 16) * D_FEAT + lane];
        float q4 = queue[(size_t)(eb.x >> 16) * D_FEAT + lane];
        float q5 = queue[(size_t)(eb.y >> 16) * D_FEAT + lane];
        float q6 = queue[(size_t)(eb.z >> 16) * D_FEAT + lane];
        float q7 = queue[(size_t)(eb.w >> 16) * D_FEAT + lane];
        acc = fmaf(q0, entry_w(ea.x), acc);
        acc = fmaf(q1, entry_w(ea.y), acc);
        acc = fmaf(q2, entry_w(ea.z), acc);
        acc = fmaf(q3, entry_w(ea.w), acc);
        acc = fmaf(q4, entry_w(eb.x), acc);
        acc = fmaf(q5, entry_w(eb.y), acc);
        acc = fmaf(q6, entry_w(eb.z), acc);
        acc = fmaf(q7, entry_w(eb.w), acc);
    }
    for (; i < n4; i += 4) {
        uint4 ea = *reinterpret_cast<const uint4*>(p + i);
        float q0 = queue[(size_t)(ea.x >> 16) * D_FEAT + lane];
        float q1 = queue[(size_t)(ea.y >> 16) * D_FEAT + lane];
        float q2 = queue[(size_t)(ea.z >> 16) * D_FEAT + lane];
        float q3 = queue[(size_t)(ea.w >> 16) * D_FEAT + lane];
        acc = fmaf(q0, entry_w(ea.x), acc);
        acc = fmaf(q1, entry_w(ea.y), acc);
        acc = fmaf(q2, entry_w(ea.z), acc);
        acc = fmaf(q3, entry_w(ea.w), acc);
    }
    out[(size_t)node * D_FEAT + lane] = acc;
}

// --- Fallback (round-1 scatter) if ws_size is ever too small ---------------
__global__ void __launch_bounds__(256)
scatter_add_kernel(const float* __restrict__ queue,
                   const float* __restrict__ weight,
                   const int* __restrict__ src,
                   const int* __restrict__ dst,
                   float* __restrict__ out) {
    long long tid = (long long)blockIdx.x * blockDim.x + threadIdx.x;
    int e = (int)(tid >> 4);
    int c = ((int)tid & 15) << 2;
    if (e >= N_EDGES) return;
    int s = src[e], d = dst[e];
    float w = weight[e];
    const float4 q = *reinterpret_cast<const float4*>(queue + (size_t)s * D_FEAT + c);
    float* o = out + (size_t)d * D_FEAT + c;
    atomicAdd(o + 0, q.x * w);
    atomicAdd(o + 1, q.y * w);
    atomicAdd(o + 2, q.z * w);
    atomicAdd(o + 3, q.w * w);
}

extern "C" void kernel_launch(void* const* d_in, const int* in_sizes, int n_in,
                              void* d_out, int out_size, void* d_ws, size_t ws_size,
                              hipStream_t stream) {
    const float* queue  = (const float*)d_in[0];
    const float* weight = (const float*)d_in[1];
    const int*   src    = (const int*)d_in[2];
    const int*   dst    = (const int*)d_in[3];
    float* out = (float*)d_out;

    // Workspace layout (all 16B-aligned at csr base):
    //   csr:    CSR_CAP unsigned   (4.0 MB)
    //   seg:    N_NODES uint2      (beg, rounded-count)
    //   counts: N_NODES int        \ zeroed together (galloc adjacent)
    //   galloc: 1 int              /
    //   cursor: N_NODES int
    const size_t csr_bytes = (size_t)CSR_CAP * sizeof(unsigned);  // 4,000,000
    const size_t need = csr_bytes + (size_t)N_NODES * sizeof(uint2)
                      + (size_t)(2 * N_NODES + 1) * sizeof(int);

    if (ws_size < need) {  // safety fallback: round-1 scatter path
        hipMemsetAsync(out, 0, (size_t)out_size * sizeof(float), stream);
        const long long total = (long long)N_EDGES * 16;
        scatter_add_kernel<<<(int)((total + 255) / 256), 256, 0, stream>>>(
            queue, weight, src, dst, out);
        return;
    }

    char* ws = (char*)d_ws;
    unsigned* csr = (unsigned*)ws;
    uint2* seg    = (uint2*)(ws + csr_bytes);
    int* counts   = (int*)(seg + N_NODES);
    int* galloc   = counts + N_NODES;
    int* cursor   = galloc + 1;

    hipMemsetAsync(counts, 0, (size_t)(N_NODES + 1) * sizeof(int), stream);

    const int e4blocks = (N_EDGES / 4 + 255) / 256;   // 782
    const int nblocks_n = (N_NODES + 255) / 256;      // 196

    hist_kernel<<<e4blocks, 256, 0, stream>>>(dst, counts);
    alloc_kernel<<<nblocks_n, 256, 0, stream>>>(counts, seg, cursor, galloc, csr);
    fill_kernel<<<e4blocks, 256, 0, stream>>>(src, dst, weight, cursor, csr);

    const int pblocks = (N_NODES + 3) / 4;            // 12500
    pull_kernel<<<pblocks, 256, 0, stream>>>(queue, csr, seg, out);
}